// Round 20
// baseline (234.782 us; speedup 1.0000x reference)
//
#include <hip/hip_runtime.h>

typedef _Float16 half8 __attribute__((ext_vector_type(8)));
typedef _Float16 half4 __attribute__((ext_vector_type(4)));
typedef float f32x4 __attribute__((ext_vector_type(4)));

__device__ __forceinline__ float eluf(float x)   { return x > 0.f ? x : __expf(x) - 1.f; }
// fast sigmoid/tanh: v_rcp instead of IEEE fdiv (rel err ~1e-7, budget 4.5e-4)
__device__ __forceinline__ float sigf(float x) {
  return __builtin_amdgcn_rcpf(1.f + __expf(-x));
}
__device__ __forceinline__ float tanhff(float x) {
  return 1.f - 2.f * __builtin_amdgcn_rcpf(__expf(2.f * x) + 1.f);
}

__device__ __forceinline__ half8 cvt8(const float* __restrict__ p) {
  f32x4 v0 = *(const f32x4*)p;
  f32x4 v1 = *(const f32x4*)(p + 4);
  half8 r;
  r[0] = (_Float16)v0[0]; r[1] = (_Float16)v0[1]; r[2] = (_Float16)v0[2]; r[3] = (_Float16)v0[3];
  r[4] = (_Float16)v1[0]; r[5] = (_Float16)v1[1]; r[6] = (_Float16)v1[2]; r[7] = (_Float16)v1[3];
  return r;
}
#define MFMA(a, b, c) __builtin_amdgcn_mfma_f32_16x16x32_f16(a, b, c, 0, 0, 0)

// ------- done normalize -> u64 bitmask  +  w_hh -> fragment-ordered f16 -----
// whhF[(((wc*4+kt)*4+ty)*64 + lg*16+lr)*8 + e] = whh[g][k],
//   g = ty*128 + wc*16 + lr, k = kt*32 + lg*8 + e  (matches k_lstm frag reads)
__global__ __launch_bounds__(256) void k_done(const unsigned char* __restrict__ raw,
                                              const float* __restrict__ whh,
                                              unsigned long long* __restrict__ dmask,
                                              _Float16* __restrict__ whhF) {
  __shared__ int f0, f1;
  if (threadIdx.x == 0) { f0 = 0; f1 = 0; }
  __syncthreads();
  int l0 = 0, l1 = 0;
  for (int i = threadIdx.x; i < 16384; i += 256)
    if (raw[i]) { if (i & 3) l0 = 1; else l1 = 1; }
  if (l0) atomicOr(&f0, 1);
  if (l1) atomicOr(&f1, 1);
  __syncthreads();
  int mode = (f0 && f1) ? 0 : (f1 ? 1 : (f0 ? 2 : 0));
  const int t = blockIdx.x;
  if (threadIdx.x < 64) {
    int i = t * 64 + threadIdx.x;
    bool v;
    if (mode == 0)      v = raw[i] != 0;
    else if (mode == 1) v = ((const int*)raw)[i] != 0;
    else                v = (((const float*)raw)[i] != 0.f);
    unsigned long long m = __ballot(v);
    if (threadIdx.x == 0) dmask[t] = m;
  }
  // w_hh permute: 65536 elems over 65536 threads
  {
    int i = blockIdx.x * 256 + threadIdx.x;
    int g = i >> 7, k = i & 127;
    int wc = (g >> 4) & 7, lr = g & 15, ty = g >> 7;
    int kt = k >> 5, lg = (k >> 3) & 3, e = k & 7;
    whhF[(((wc * 4 + kt) * 4 + ty) * 64 + lg * 16 + lr) * 8 + e] = (_Float16)whh[i];
  }
}

// ---------------- conv stack + readin + xgates (all-MFMA, R13 proven) -------
__global__ __launch_bounds__(512, 4) void k_conv(
    const float* __restrict__ inp,
    const float* __restrict__ c1w, const float* __restrict__ c1b,
    const float* __restrict__ c2w, const float* __restrict__ c2b,
    const float* __restrict__ c3w, const float* __restrict__ c3b,
    const float* __restrict__ riw, const float* __restrict__ rib,
    const float* __restrict__ wih, const float* __restrict__ bih,
    const float* __restrict__ bhh,
    _Float16* __restrict__ xgh)   // [256 t][512 gate][64 b] f16
{
  extern __shared__ char L[];
  unsigned*  LUT32 = (unsigned*)L;              // [32] u32, 128 B
  _Float16*  ic1   = (_Float16*)(L + 128);      // [256][32] f16 swz, 16384 B
  _Float16*  a1t   = (_Float16*)(L + 16512);    // [16][1160] f16, 37120 B
  _Float16*  a2    = (_Float16*)(L + 53632);    // [32][128] f16 swz, 8192 B
  _Float16*  c2wL  = (_Float16*)(L + 61824);    // [32 o][9 tap][32 i] f16, 18432 B
  _Float16*  ft    = (_Float16*)(L + 128);      // overlay (ic1/a1t dead)
  _Float16*  yb    = (_Float16*)(L + 8320);     // overlay

  const int tid  = threadIdx.x;
  const int lane = tid & 63;
  const int wv   = tid >> 6;        // 0..7
  const int lr   = lane & 15;
  const int lg   = lane >> 4;
  const int t    = blockIdx.x >> 1;
  const int bh   = blockIdx.x & 1;

  const int ntl  = wv & 1;          // n-tile for conv1/conv2 (o = ntl*16+lr)
  const int mq   = wv >> 1;         // m-group
  const int o1   = ntl * 16 + lr;

  if (tid < 32) {
    unsigned v = 0xFFFFFFFFu;
    if (tid < 27) { int c = tid / 9, r9 = tid % 9; v = (unsigned)(c | ((r9 / 3) << 8) | ((r9 % 3) << 16)); }
    LUT32[tid] = v;
  }

  // stage c2w -> LDS transposed [o][tap][i] (f16)
  if (tid < 128) {
    const int o = tid >> 2, lg2 = tid & 3;
    const float* src = c2w + o * 288 + lg2 * 72;
    #pragma unroll 4
    for (int j = 0; j < 72; ++j) {
      int i = lg2 * 8 + j / 9, tap = j % 9;
      c2wL[(o * 9 + tap) * 32 + i] = (_Float16)src[j];
    }
  }

  half8 B1;
  #pragma unroll
  for (int e = 0; e < 8; ++e) {
    int k = lg * 8 + e;
    B1[e] = (_Float16)((k < 27) ? c1w[o1 * 27 + k] : 0.f);
  }
  const float b1o = c1b[o1];
  const float b2o = c2b[o1];

  for (int ch = 0; ch < 2; ++ch) {        // 2 chunks x 16 samples
    __syncthreads();                      // also orders c2wL staging (ch=0)
    for (int i = tid; i < 18560 / 2; i += 512) ((unsigned*)a1t)[i] = 0u;
    {
      const size_t n0 = (size_t)(t * 64 + bh * 32 + ch * 16) * 147;
      #pragma unroll 4
      for (int j = 0; j < 16; ++j) {
        int e = tid + j * 512;            // 0..8191
        int row = e >> 5, k = e & 31;
        int s = row >> 4, pos = row & 15;
        int p = pos >> 2, q = pos & 3;
        unsigned lut = LUT32[k];
        float v = 0.f;
        if (lut != 0xFFFFFFFFu) {
          int c = lut & 0xFF, dp = (lut >> 8) & 0xFF, dq = (lut >> 16) & 0xFF;
          int pp = 2 * p + dp - 1, qq = 2 * q + dq - 1;
          if ((unsigned)pp < 7u && (unsigned)qq < 7u)
            v = inp[n0 + s * 147 + qq * 21 + pp * 3 + c];
        }
        ic1[row * 32 + (k ^ ((row & 3) << 3))] = (_Float16)v;
      }
    }
    __syncthreads();
    #pragma unroll
    for (int mi = 0; mi < 4; ++mi) {
      const int mtile = mq * 4 + mi;
      const int rowA  = mtile * 16 + lr;
      half8 a = *(const half8*)(ic1 + rowA * 32 + ((lg * 8) ^ ((rowA & 3) << 3)));
      f32x4 acc; acc[0] = b1o; acc[1] = b1o; acc[2] = b1o; acc[3] = b1o;
      acc = MFMA(a, B1, acc);
      #pragma unroll
      for (int r = 0; r < 4; ++r) {
        int m1 = mtile * 16 + lg * 4 + r;
        int s = m1 >> 4, pos = m1 & 15;
        int p = pos >> 2, q = pos & 3;
        int xy = (p + 1) * 6 + (q + 1);
        a1t[s * 1160 + xy * 32 + (o1 ^ ((xy & 3) << 3))] = (_Float16)eluf(acc[r]);
      }
    }
    __syncthreads();
    {
      f32x4 acc; acc[0] = b2o; acc[1] = b2o; acc[2] = b2o; acc[3] = b2o;
      const int rowm = mq * 16 + lr;
      const int s2 = rowm >> 2, pos2 = rowm & 3;
      const int p2 = pos2 >> 1, q2 = pos2 & 1;
      #pragma unroll
      for (int tap = 0; tap < 9; ++tap) {
        const int dp = tap / 3, dq = tap % 3;
        const int xy2 = (2 * p2 + dp) * 6 + (2 * q2 + dq);
        half8 a  = *(const half8*)(a1t + s2 * 1160 + xy2 * 32 + ((lg * 8) ^ ((xy2 & 3) << 3)));
        half8 b2 = *(const half8*)(c2wL + (o1 * 9 + tap) * 32 + lg * 8);
        acc = MFMA(a, b2, acc);
      }
      #pragma unroll
      for (int r = 0; r < 4; ++r) {
        int m = mq * 16 + lg * 4 + r;
        int s2w = m >> 2, pos = m & 3;
        int arow = ch * 16 + s2w;
        int col = o1 * 4 + pos;
        a2[arow * 128 + (col ^ ((arow & 7) << 3))] = (_Float16)eluf(acc[r]);
      }
    }
  }
  __syncthreads();

  // conv3 GEMM: M=32, K=128, N=128
  {
    half8 B3[4];
    #pragma unroll
    for (int kt = 0; kt < 4; ++kt) {
      half8 b;
      #pragma unroll
      for (int e = 0; e < 8; ++e) {
        int k = kt * 32 + lg * 8 + e;
        int i = k >> 2, pos = k & 3;
        int widx = 4 + (pos >> 1) * 3 + (pos & 1);
        b[e] = (_Float16)c3w[(wv * 16 + lr) * 288 + i * 9 + widx];
      }
      B3[kt] = b;
    }
    float bb = c3b[wv * 16 + lr];
    #pragma unroll
    for (int mt = 0; mt < 2; ++mt) {
      f32x4 acc; acc[0] = bb; acc[1] = bb; acc[2] = bb; acc[3] = bb;
      const int row = mt * 16 + lr;
      #pragma unroll
      for (int kt = 0; kt < 4; ++kt) {
        half8 a = *(const half8*)(a2 + row * 128 + ((kt * 32 + lg * 8) ^ ((row & 7) << 3)));
        acc = MFMA(a, B3[kt], acc);
      }
      #pragma unroll
      for (int r = 0; r < 4; ++r) {
        int m = mt * 16 + lg * 4 + r;
        ft[m * 128 + ((wv * 16 + lr) ^ ((m & 7) << 3))] = (_Float16)eluf(acc[r]);
      }
    }
  }
  __syncthreads();

  // GEMM1: y = ft @ riw^T + rib
  {
    half8 R1[4];
    #pragma unroll
    for (int kt = 0; kt < 4; ++kt)
      R1[kt] = cvt8(riw + (wv * 16 + lr) * 128 + kt * 32 + lg * 8);
    float bb = rib[wv * 16 + lr];
    #pragma unroll
    for (int mt = 0; mt < 2; ++mt) {
      f32x4 acc; acc[0] = bb; acc[1] = bb; acc[2] = bb; acc[3] = bb;
      const int row = mt * 16 + lr;
      #pragma unroll
      for (int kt = 0; kt < 4; ++kt) {
        half8 a = *(const half8*)(ft + row * 128 + ((kt * 32 + lg * 8) ^ ((row & 7) << 3)));
        acc = MFMA(a, R1[kt], acc);
      }
      #pragma unroll
      for (int r = 0; r < 4; ++r) {
        int m = mt * 16 + lg * 4 + r;
        yb[m * 128 + ((wv * 16 + lr) ^ ((m & 7) << 3))] = (_Float16)acc[r];
      }
    }
  }
  __syncthreads();

  // GEMM2: xg = y @ wih^T + (bih + bhh)
  {
    #pragma unroll
    for (int mt = 0; mt < 2; ++mt) {
      const int row = mt * 16 + lr;
      half8 a[4];
      #pragma unroll
      for (int kt = 0; kt < 4; ++kt)
        a[kt] = *(const half8*)(yb + row * 128 + ((kt * 32 + lg * 8) ^ ((row & 7) << 3)));
      #pragma unroll
      for (int ty = 0; ty < 4; ++ty) {
        int g = ty * 128 + wv * 16 + lr;
        float bg = bih[g] + bhh[g];
        f32x4 acc; acc[0] = bg; acc[1] = bg; acc[2] = bg; acc[3] = bg;
        #pragma unroll
        for (int kt = 0; kt < 4; ++kt) {
          half8 w = cvt8(wih + g * 128 + kt * 32 + lg * 8);
          acc = MFMA(a[kt], w, acc);
        }
        half4 h4;
        h4[0] = (_Float16)acc[0]; h4[1] = (_Float16)acc[1];
        h4[2] = (_Float16)acc[2]; h4[3] = (_Float16)acc[3];
        *(half4*)(xgh + ((size_t)t * 512 + g) * 64 + bh * 32 + mt * 16 + lg * 4) = h4;
      }
    }
  }
}

// ---------------- windowed LSTM (16 steps, MFMA) + readout ------------------
// block = (t, b-quarter) = 16 samples, 512 thr / 8 waves, grid 1024.
// R18 (full unroll): ILP but spill -> 115 us @ 40% occ. R19 (unroll 1):
// no spill, 75% occ, but serial kt chain -> 148 us. THIS ROUND: unroll 2 —
// transients ~24 regs (live ~56 < 64, still spill-free) while the compiler
// overlaps iteration k+1's loads under iteration k's MFMAs.
__global__ __launch_bounds__(512, 4) void k_lstm(
    const _Float16* __restrict__ whhF, const float* __restrict__ bih,
    const float* __restrict__ bhh, const _Float16* __restrict__ xgh,
    const unsigned long long* __restrict__ dmask,
    const float* __restrict__ row_, const float* __restrict__ rob,
    float* __restrict__ out)
{
  __shared__ _Float16 H[2][16 * 128];   // 8 KB, XOR-swizzled rows

  const int tid  = threadIdx.x;
  const int lane = tid & 63;
  const int wv   = tid >> 6;            // cell group: cells wv*16 + lr
  const int lr   = lane & 15, lg = lane >> 4;
  const int xcd  = blockIdx.x & 7;
  const int j    = blockIdx.x >> 3;     // 0..127 per XCD
  const int t    = (xcd << 5) + (j >> 2);
  const int bq   = j & 3;               // b-quarter
  const int bbase = bq * 16;

  const _Float16* wbase = whhF + (size_t)wv * 8192 + lane * 8;  // frag base

  for (int i = tid; i < 16 * 128 / 2; i += 512) ((unsigned*)H[0])[i] = 0u;

  float cc[4];   // [r]: local sample lg*4 + r, cell wv*16+lr
  #pragma unroll
  for (int r = 0; r < 4; ++r) cc[r] = 0.f;

  for (int st = 0; st < 16; ++st) {
    const int ts = t + st - 15;
    _Float16* Hr = H[st & 1];
    _Float16* Hw = H[(st & 1) ^ 1];
    __syncthreads();
    const bool hasX = (ts >= 0);
    const unsigned long long wm =
        (st < 15 && ts + 1 >= 0) ? dmask[ts + 1] : 0ULL;
    const _Float16* xb = xgh + (size_t)ts * 32768 + bbase;
    f32x4 acc[4];   // [ty]
    if (hasX) {
      #pragma unroll
      for (int ty = 0; ty < 4; ++ty) {
        half4 p = *(const half4*)(xb + (ty * 128 + wv * 16 + lr) * 64 + lg * 4);
        acc[ty][0] = (float)p[0]; acc[ty][1] = (float)p[1];
        acc[ty][2] = (float)p[2]; acc[ty][3] = (float)p[3];
      }
    } else {
      // lazy bias path (only blocks with t < 15 ever take this branch)
      #pragma unroll
      for (int ty = 0; ty < 4; ++ty) {
        int g = ty * 128 + wv * 16 + lr;
        float b = bih[g] + bhh[g];
        acc[ty][0] = b; acc[ty][1] = b; acc[ty][2] = b; acc[ty][3] = b;
      }
    }
    #pragma unroll 2
    for (int kt = 0; kt < 4; ++kt) {
      half8 a0 = *(const half8*)(Hr + lr * 128 + ((kt * 32 + lg * 8) ^ ((lr & 7) << 3)));
      #pragma unroll
      for (int ty = 0; ty < 4; ++ty) {
        half8 wf = *(const half8*)(wbase + (kt * 4 + ty) * 512);
        acc[ty] = MFMA(a0, wf, acc[ty]);
      }
    }
    const unsigned mnib = (unsigned)(wm >> (bbase + lg * 4)) & 15u;
    #pragma unroll
    for (int r = 0; r < 4; ++r) {
      const int s_ = lg * 4 + r;                  // local sample 0..15
      const bool d = (mnib >> r) & 1u;
      float iv = sigf(acc[0][r]);
      float fv = sigf(acc[1][r]);
      float gv = tanhff(acc[2][r]);
      float ov = sigf(acc[3][r]);
      float cn = fmaf(fv, cc[r], iv * gv);
      float hn = ov * tanhff(cn);
      cc[r] = d ? 0.f : cn;
      Hw[s_ * 128 + ((wv * 16 + lr) ^ ((s_ & 7) << 3))] = (_Float16)(d ? 0.f : hn);
    }
  }
  __syncthreads();

  // readout: out = h_final @ row_^T + rob  (h_final in H[0] after st=15)
  float rb2 = rob[wv * 16 + lr];
  {
    const int row = lr;
    f32x4 acc; acc[0] = rb2; acc[1] = rb2; acc[2] = rb2; acc[3] = rb2;
    #pragma unroll 2
    for (int kt = 0; kt < 4; ++kt) {
      half8 R = cvt8(row_ + (wv * 16 + lr) * 128 + kt * 32 + lg * 8);
      half8 a = *(const half8*)(H[0] + row * 128 + ((kt * 32 + lg * 8) ^ ((row & 7) << 3)));
      acc = MFMA(a, R, acc);
    }
    #pragma unroll
    for (int r = 0; r < 4; ++r) {
      int s = lg * 4 + r;
      out[(size_t)(t * 64 + bbase + s) * 128 + wv * 16 + lr] = acc[r];
    }
  }
}

extern "C" void kernel_launch(void* const* d_in, const int* in_sizes, int n_in,
                              void* d_out, int out_size, void* d_ws, size_t ws_size,
                              hipStream_t stream) {
  const float* inp = (const float*)d_in[0];
  const void*  don = d_in[1];
  const float* c1w = (const float*)d_in[2];
  const float* c1b = (const float*)d_in[3];
  const float* c2w = (const float*)d_in[4];
  const float* c2b = (const float*)d_in[5];
  const float* c3w = (const float*)d_in[6];
  const float* c3b = (const float*)d_in[7];
  const float* riw = (const float*)d_in[8];
  const float* rib = (const float*)d_in[9];
  const float* wih = (const float*)d_in[10];
  const float* whh = (const float*)d_in[11];
  const float* bih = (const float*)d_in[12];
  const float* bhh = (const float*)d_in[13];
  const float* row_ = (const float*)d_in[14];
  const float* rob = (const float*)d_in[15];

  unsigned long long* dmask = (unsigned long long*)d_ws;        // 2 KB @ 0
  _Float16* whhF = (_Float16*)((char*)d_ws + 16384);            // 128 KB
  _Float16* xgh  = (_Float16*)((char*)d_ws + 16384 + 131072);   // 16.8 MB f16

  (void)hipFuncSetAttribute((const void*)k_conv,
                            hipFuncAttributeMaxDynamicSharedMemorySize, 80256);

  k_done<<<256, 256, 0, stream>>>((const unsigned char*)don, whh, dmask, whhF);
  k_conv<<<512, 512, 80256, stream>>>(inp, c1w, c1b, c2w, c2b, c3w, c3b,
                                      riw, rib, wih, bih, bhh, xgh);
  k_lstm<<<1024, 512, 0, stream>>>(whhF, bih, bhh, xgh, dmask, row_, rob,
                                   (float*)d_out);
}

// Round 21
// 186.716 us; speedup vs baseline: 1.2574x; 1.2574x over previous
//
#include <hip/hip_runtime.h>

typedef _Float16 half8 __attribute__((ext_vector_type(8)));
typedef _Float16 half4 __attribute__((ext_vector_type(4)));
typedef float f32x4 __attribute__((ext_vector_type(4)));

__device__ __forceinline__ float eluf(float x)   { return x > 0.f ? x : __expf(x) - 1.f; }
// fast sigmoid/tanh: v_rcp instead of IEEE fdiv (rel err ~1e-7, budget 4.5e-4)
__device__ __forceinline__ float sigf(float x) {
  return __builtin_amdgcn_rcpf(1.f + __expf(-x));
}
__device__ __forceinline__ float tanhff(float x) {
  return 1.f - 2.f * __builtin_amdgcn_rcpf(__expf(2.f * x) + 1.f);
}

__device__ __forceinline__ half8 cvt8(const float* __restrict__ p) {
  f32x4 v0 = *(const f32x4*)p;
  f32x4 v1 = *(const f32x4*)(p + 4);
  half8 r;
  r[0] = (_Float16)v0[0]; r[1] = (_Float16)v0[1]; r[2] = (_Float16)v0[2]; r[3] = (_Float16)v0[3];
  r[4] = (_Float16)v1[0]; r[5] = (_Float16)v1[1]; r[6] = (_Float16)v1[2]; r[7] = (_Float16)v1[3];
  return r;
}
#define MFMA(a, b, c) __builtin_amdgcn_mfma_f32_16x16x32_f16(a, b, c, 0, 0, 0)

// ------- done normalize -> u64 bitmask  +  w_hh -> fragment-ordered f16 -----
// whhF[(((wc*4+kt)*4+ty)*64 + lg*16+lr)*8 + e] = whh[g][k],
//   g = ty*128 + wc*16 + lr, k = kt*32 + lg*8 + e  (matches k_lstm frag reads)
__global__ __launch_bounds__(256) void k_done(const unsigned char* __restrict__ raw,
                                              const float* __restrict__ whh,
                                              unsigned long long* __restrict__ dmask,
                                              _Float16* __restrict__ whhF) {
  __shared__ int f0, f1;
  if (threadIdx.x == 0) { f0 = 0; f1 = 0; }
  __syncthreads();
  int l0 = 0, l1 = 0;
  for (int i = threadIdx.x; i < 16384; i += 256)
    if (raw[i]) { if (i & 3) l0 = 1; else l1 = 1; }
  if (l0) atomicOr(&f0, 1);
  if (l1) atomicOr(&f1, 1);
  __syncthreads();
  int mode = (f0 && f1) ? 0 : (f1 ? 1 : (f0 ? 2 : 0));
  const int t = blockIdx.x;
  if (threadIdx.x < 64) {
    int i = t * 64 + threadIdx.x;
    bool v;
    if (mode == 0)      v = raw[i] != 0;
    else if (mode == 1) v = ((const int*)raw)[i] != 0;
    else                v = (((const float*)raw)[i] != 0.f);
    unsigned long long m = __ballot(v);
    if (threadIdx.x == 0) dmask[t] = m;
  }
  // w_hh permute: 65536 elems over 65536 threads
  {
    int i = blockIdx.x * 256 + threadIdx.x;
    int g = i >> 7, k = i & 127;
    int wc = (g >> 4) & 7, lr = g & 15, ty = g >> 7;
    int kt = k >> 5, lg = (k >> 3) & 3, e = k & 7;
    whhF[(((wc * 4 + kt) * 4 + ty) * 64 + lg * 16 + lr) * 8 + e] = (_Float16)whh[i];
  }
}

// ---------------- conv stack + readin + xgates (all-MFMA, R13 proven) -------
__global__ __launch_bounds__(512, 4) void k_conv(
    const float* __restrict__ inp,
    const float* __restrict__ c1w, const float* __restrict__ c1b,
    const float* __restrict__ c2w, const float* __restrict__ c2b,
    const float* __restrict__ c3w, const float* __restrict__ c3b,
    const float* __restrict__ riw, const float* __restrict__ rib,
    const float* __restrict__ wih, const float* __restrict__ bih,
    const float* __restrict__ bhh,
    _Float16* __restrict__ xgh)   // [256 t][512 gate][64 b] f16
{
  extern __shared__ char L[];
  unsigned*  LUT32 = (unsigned*)L;              // [32] u32, 128 B
  _Float16*  ic1   = (_Float16*)(L + 128);      // [256][32] f16 swz, 16384 B
  _Float16*  a1t   = (_Float16*)(L + 16512);    // [16][1160] f16, 37120 B
  _Float16*  a2    = (_Float16*)(L + 53632);    // [32][128] f16 swz, 8192 B
  _Float16*  c2wL  = (_Float16*)(L + 61824);    // [32 o][9 tap][32 i] f16, 18432 B
  _Float16*  ft    = (_Float16*)(L + 128);      // overlay (ic1/a1t dead)
  _Float16*  yb    = (_Float16*)(L + 8320);     // overlay

  const int tid  = threadIdx.x;
  const int lane = tid & 63;
  const int wv   = tid >> 6;        // 0..7
  const int lr   = lane & 15;
  const int lg   = lane >> 4;
  const int t    = blockIdx.x >> 1;
  const int bh   = blockIdx.x & 1;

  const int ntl  = wv & 1;          // n-tile for conv1/conv2 (o = ntl*16+lr)
  const int mq   = wv >> 1;         // m-group
  const int o1   = ntl * 16 + lr;

  if (tid < 32) {
    unsigned v = 0xFFFFFFFFu;
    if (tid < 27) { int c = tid / 9, r9 = tid % 9; v = (unsigned)(c | ((r9 / 3) << 8) | ((r9 % 3) << 16)); }
    LUT32[tid] = v;
  }

  // stage c2w -> LDS transposed [o][tap][i] (f16)
  if (tid < 128) {
    const int o = tid >> 2, lg2 = tid & 3;
    const float* src = c2w + o * 288 + lg2 * 72;
    #pragma unroll 4
    for (int j = 0; j < 72; ++j) {
      int i = lg2 * 8 + j / 9, tap = j % 9;
      c2wL[(o * 9 + tap) * 32 + i] = (_Float16)src[j];
    }
  }

  half8 B1;
  #pragma unroll
  for (int e = 0; e < 8; ++e) {
    int k = lg * 8 + e;
    B1[e] = (_Float16)((k < 27) ? c1w[o1 * 27 + k] : 0.f);
  }
  const float b1o = c1b[o1];
  const float b2o = c2b[o1];

  for (int ch = 0; ch < 2; ++ch) {        // 2 chunks x 16 samples
    __syncthreads();                      // also orders c2wL staging (ch=0)
    for (int i = tid; i < 18560 / 2; i += 512) ((unsigned*)a1t)[i] = 0u;
    {
      const size_t n0 = (size_t)(t * 64 + bh * 32 + ch * 16) * 147;
      #pragma unroll 4
      for (int j = 0; j < 16; ++j) {
        int e = tid + j * 512;            // 0..8191
        int row = e >> 5, k = e & 31;
        int s = row >> 4, pos = row & 15;
        int p = pos >> 2, q = pos & 3;
        unsigned lut = LUT32[k];
        float v = 0.f;
        if (lut != 0xFFFFFFFFu) {
          int c = lut & 0xFF, dp = (lut >> 8) & 0xFF, dq = (lut >> 16) & 0xFF;
          int pp = 2 * p + dp - 1, qq = 2 * q + dq - 1;
          if ((unsigned)pp < 7u && (unsigned)qq < 7u)
            v = inp[n0 + s * 147 + qq * 21 + pp * 3 + c];
        }
        ic1[row * 32 + (k ^ ((row & 3) << 3))] = (_Float16)v;
      }
    }
    __syncthreads();
    #pragma unroll
    for (int mi = 0; mi < 4; ++mi) {
      const int mtile = mq * 4 + mi;
      const int rowA  = mtile * 16 + lr;
      half8 a = *(const half8*)(ic1 + rowA * 32 + ((lg * 8) ^ ((rowA & 3) << 3)));
      f32x4 acc; acc[0] = b1o; acc[1] = b1o; acc[2] = b1o; acc[3] = b1o;
      acc = MFMA(a, B1, acc);
      #pragma unroll
      for (int r = 0; r < 4; ++r) {
        int m1 = mtile * 16 + lg * 4 + r;
        int s = m1 >> 4, pos = m1 & 15;
        int p = pos >> 2, q = pos & 3;
        int xy = (p + 1) * 6 + (q + 1);
        a1t[s * 1160 + xy * 32 + (o1 ^ ((xy & 3) << 3))] = (_Float16)eluf(acc[r]);
      }
    }
    __syncthreads();
    {
      f32x4 acc; acc[0] = b2o; acc[1] = b2o; acc[2] = b2o; acc[3] = b2o;
      const int rowm = mq * 16 + lr;
      const int s2 = rowm >> 2, pos2 = rowm & 3;
      const int p2 = pos2 >> 1, q2 = pos2 & 1;
      #pragma unroll
      for (int tap = 0; tap < 9; ++tap) {
        const int dp = tap / 3, dq = tap % 3;
        const int xy2 = (2 * p2 + dp) * 6 + (2 * q2 + dq);
        half8 a  = *(const half8*)(a1t + s2 * 1160 + xy2 * 32 + ((lg * 8) ^ ((xy2 & 3) << 3)));
        half8 b2 = *(const half8*)(c2wL + (o1 * 9 + tap) * 32 + lg * 8);
        acc = MFMA(a, b2, acc);
      }
      #pragma unroll
      for (int r = 0; r < 4; ++r) {
        int m = mq * 16 + lg * 4 + r;
        int s2w = m >> 2, pos = m & 3;
        int arow = ch * 16 + s2w;
        int col = o1 * 4 + pos;
        a2[arow * 128 + (col ^ ((arow & 7) << 3))] = (_Float16)eluf(acc[r]);
      }
    }
  }
  __syncthreads();

  // conv3 GEMM: M=32, K=128, N=128
  {
    half8 B3[4];
    #pragma unroll
    for (int kt = 0; kt < 4; ++kt) {
      half8 b;
      #pragma unroll
      for (int e = 0; e < 8; ++e) {
        int k = kt * 32 + lg * 8 + e;
        int i = k >> 2, pos = k & 3;
        int widx = 4 + (pos >> 1) * 3 + (pos & 1);
        b[e] = (_Float16)c3w[(wv * 16 + lr) * 288 + i * 9 + widx];
      }
      B3[kt] = b;
    }
    float bb = c3b[wv * 16 + lr];
    #pragma unroll
    for (int mt = 0; mt < 2; ++mt) {
      f32x4 acc; acc[0] = bb; acc[1] = bb; acc[2] = bb; acc[3] = bb;
      const int row = mt * 16 + lr;
      #pragma unroll
      for (int kt = 0; kt < 4; ++kt) {
        half8 a = *(const half8*)(a2 + row * 128 + ((kt * 32 + lg * 8) ^ ((row & 7) << 3)));
        acc = MFMA(a, B3[kt], acc);
      }
      #pragma unroll
      for (int r = 0; r < 4; ++r) {
        int m = mt * 16 + lg * 4 + r;
        ft[m * 128 + ((wv * 16 + lr) ^ ((m & 7) << 3))] = (_Float16)eluf(acc[r]);
      }
    }
  }
  __syncthreads();

  // GEMM1: y = ft @ riw^T + rib
  {
    half8 R1[4];
    #pragma unroll
    for (int kt = 0; kt < 4; ++kt)
      R1[kt] = cvt8(riw + (wv * 16 + lr) * 128 + kt * 32 + lg * 8);
    float bb = rib[wv * 16 + lr];
    #pragma unroll
    for (int mt = 0; mt < 2; ++mt) {
      f32x4 acc; acc[0] = bb; acc[1] = bb; acc[2] = bb; acc[3] = bb;
      const int row = mt * 16 + lr;
      #pragma unroll
      for (int kt = 0; kt < 4; ++kt) {
        half8 a = *(const half8*)(ft + row * 128 + ((kt * 32 + lg * 8) ^ ((row & 7) << 3)));
        acc = MFMA(a, R1[kt], acc);
      }
      #pragma unroll
      for (int r = 0; r < 4; ++r) {
        int m = mt * 16 + lg * 4 + r;
        yb[m * 128 + ((wv * 16 + lr) ^ ((m & 7) << 3))] = (_Float16)acc[r];
      }
    }
  }
  __syncthreads();

  // GEMM2: xg = y @ wih^T + (bih + bhh)
  {
    #pragma unroll
    for (int mt = 0; mt < 2; ++mt) {
      const int row = mt * 16 + lr;
      half8 a[4];
      #pragma unroll
      for (int kt = 0; kt < 4; ++kt)
        a[kt] = *(const half8*)(yb + row * 128 + ((kt * 32 + lg * 8) ^ ((row & 7) << 3)));
      #pragma unroll
      for (int ty = 0; ty < 4; ++ty) {
        int g = ty * 128 + wv * 16 + lr;
        float bg = bih[g] + bhh[g];
        f32x4 acc; acc[0] = bg; acc[1] = bg; acc[2] = bg; acc[3] = bg;
        #pragma unroll
        for (int kt = 0; kt < 4; ++kt) {
          half8 w = cvt8(wih + g * 128 + kt * 32 + lg * 8);
          acc = MFMA(a[kt], w, acc);
        }
        half4 h4;
        h4[0] = (_Float16)acc[0]; h4[1] = (_Float16)acc[1];
        h4[2] = (_Float16)acc[2]; h4[3] = (_Float16)acc[3];
        *(half4*)(xgh + ((size_t)t * 512 + g) * 64 + bh * 32 + mt * 16 + lg * 4) = h4;
      }
    }
  }
}

// ---------------- windowed LSTM (16 steps, MFMA) + readout ------------------
// block = (t, b-quarter) = 16 samples, 512 thr / 8 waves, grid 1024.
// R18 configuration — the measured optimum of the {full, 2, 1} unroll sweep:
// full unroll gives ILP (loads hoisted over MFMAs) at the cost of a small
// scratch spill; 115.6 us vs 148 (unroll 1, no spill) and 174 (unroll 2).
__global__ __launch_bounds__(512, 4) void k_lstm(
    const _Float16* __restrict__ whhF, const float* __restrict__ bih,
    const float* __restrict__ bhh, const _Float16* __restrict__ xgh,
    const unsigned long long* __restrict__ dmask,
    const float* __restrict__ row_, const float* __restrict__ rob,
    float* __restrict__ out)
{
  __shared__ _Float16 H[2][16 * 128];   // 8 KB, XOR-swizzled rows

  const int tid  = threadIdx.x;
  const int lane = tid & 63;
  const int wv   = tid >> 6;            // cell group: cells wv*16 + lr
  const int lr   = lane & 15, lg = lane >> 4;
  const int xcd  = blockIdx.x & 7;
  const int j    = blockIdx.x >> 3;     // 0..127 per XCD
  const int t    = (xcd << 5) + (j >> 2);
  const int bq   = j & 3;               // b-quarter
  const int bbase = bq * 16;

  const _Float16* wbase = whhF + (size_t)wv * 8192 + lane * 8;  // frag base

  float b0[4];
  #pragma unroll
  for (int ty = 0; ty < 4; ++ty) {
    int g = ty * 128 + wv * 16 + lr;
    b0[ty] = bih[g] + bhh[g];
  }

  for (int i = tid; i < 16 * 128 / 2; i += 512) ((unsigned*)H[0])[i] = 0u;

  float cc[4];   // [r]: local sample lg*4 + r, cell wv*16+lr
  #pragma unroll
  for (int r = 0; r < 4; ++r) cc[r] = 0.f;

  for (int st = 0; st < 16; ++st) {
    const int ts = t + st - 15;
    _Float16* Hr = H[st & 1];
    _Float16* Hw = H[(st & 1) ^ 1];
    __syncthreads();
    const bool hasX = (ts >= 0);
    const unsigned long long wm =
        (st < 15 && ts + 1 >= 0) ? dmask[ts + 1] : 0ULL;
    const _Float16* xb = xgh + (size_t)ts * 32768 + bbase;
    f32x4 acc[4];   // [ty]
    if (hasX) {
      #pragma unroll
      for (int ty = 0; ty < 4; ++ty) {
        half4 p = *(const half4*)(xb + (ty * 128 + wv * 16 + lr) * 64 + lg * 4);
        acc[ty][0] = (float)p[0]; acc[ty][1] = (float)p[1];
        acc[ty][2] = (float)p[2]; acc[ty][3] = (float)p[3];
      }
    } else {
      #pragma unroll
      for (int ty = 0; ty < 4; ++ty) {
        acc[ty][0] = b0[ty]; acc[ty][1] = b0[ty];
        acc[ty][2] = b0[ty]; acc[ty][3] = b0[ty];
      }
    }
    #pragma unroll
    for (int kt = 0; kt < 4; ++kt) {
      half8 a0 = *(const half8*)(Hr + lr * 128 + ((kt * 32 + lg * 8) ^ ((lr & 7) << 3)));
      // per-ty load->MFMA pairs (R18 best)
      #pragma unroll
      for (int ty = 0; ty < 4; ++ty) {
        half8 wf = *(const half8*)(wbase + (kt * 4 + ty) * 512);
        acc[ty] = MFMA(a0, wf, acc[ty]);
      }
    }
    const unsigned mnib = (unsigned)(wm >> (bbase + lg * 4)) & 15u;
    #pragma unroll
    for (int r = 0; r < 4; ++r) {
      const int s_ = lg * 4 + r;                  // local sample 0..15
      const bool d = (mnib >> r) & 1u;
      float iv = sigf(acc[0][r]);
      float fv = sigf(acc[1][r]);
      float gv = tanhff(acc[2][r]);
      float ov = sigf(acc[3][r]);
      float cn = fmaf(fv, cc[r], iv * gv);
      float hn = ov * tanhff(cn);
      cc[r] = d ? 0.f : cn;
      Hw[s_ * 128 + ((wv * 16 + lr) ^ ((s_ & 7) << 3))] = (_Float16)(d ? 0.f : hn);
    }
  }
  __syncthreads();

  // readout: out = h_final @ row_^T + rob  (h_final in H[0] after st=15)
  float rb2 = rob[wv * 16 + lr];
  {
    const int row = lr;
    f32x4 acc; acc[0] = rb2; acc[1] = rb2; acc[2] = rb2; acc[3] = rb2;
    #pragma unroll
    for (int kt = 0; kt < 4; ++kt) {
      half8 R = cvt8(row_ + (wv * 16 + lr) * 128 + kt * 32 + lg * 8);
      half8 a = *(const half8*)(H[0] + row * 128 + ((kt * 32 + lg * 8) ^ ((row & 7) << 3)));
      acc = MFMA(a, R, acc);
    }
    #pragma unroll
    for (int r = 0; r < 4; ++r) {
      int s = lg * 4 + r;
      out[(size_t)(t * 64 + bbase + s) * 128 + wv * 16 + lr] = acc[r];
    }
  }
}

extern "C" void kernel_launch(void* const* d_in, const int* in_sizes, int n_in,
                              void* d_out, int out_size, void* d_ws, size_t ws_size,
                              hipStream_t stream) {
  const float* inp = (const float*)d_in[0];
  const void*  don = d_in[1];
  const float* c1w = (const float*)d_in[2];
  const float* c1b = (const float*)d_in[3];
  const float* c2w = (const float*)d_in[4];
  const float* c2b = (const float*)d_in[5];
  const float* c3w = (const float*)d_in[6];
  const float* c3b = (const float*)d_in[7];
  const float* riw = (const float*)d_in[8];
  const float* rib = (const float*)d_in[9];
  const float* wih = (const float*)d_in[10];
  const float* whh = (const float*)d_in[11];
  const float* bih = (const float*)d_in[12];
  const float* bhh = (const float*)d_in[13];
  const float* row_ = (const float*)d_in[14];
  const float* rob = (const float*)d_in[15];

  unsigned long long* dmask = (unsigned long long*)d_ws;        // 2 KB @ 0
  _Float16* whhF = (_Float16*)((char*)d_ws + 16384);            // 128 KB
  _Float16* xgh  = (_Float16*)((char*)d_ws + 16384 + 131072);   // 16.8 MB f16

  (void)hipFuncSetAttribute((const void*)k_conv,
                            hipFuncAttributeMaxDynamicSharedMemorySize, 80256);

  k_done<<<256, 256, 0, stream>>>((const unsigned char*)don, whh, dmask, whhF);
  k_conv<<<512, 512, 80256, stream>>>(inp, c1w, c1b, c2w, c2b, c3w, c3b,
                                      riw, rib, wih, bih, bhh, xgh);
  k_lstm<<<1024, 512, 0, stream>>>(whhF, bih, bhh, xgh, dmask, row_, rob,
                                   (float*)d_out);
}

// Round 22
// 186.504 us; speedup vs baseline: 1.2589x; 1.0011x over previous
//
#include <hip/hip_runtime.h>

typedef _Float16 half8 __attribute__((ext_vector_type(8)));
typedef _Float16 half4 __attribute__((ext_vector_type(4)));
typedef float f32x4 __attribute__((ext_vector_type(4)));

__device__ __forceinline__ float eluf(float x)   { return x > 0.f ? x : __expf(x) - 1.f; }
// fast sigmoid/tanh: v_rcp instead of IEEE fdiv (rel err ~1e-7, budget 4.5e-4)
__device__ __forceinline__ float sigf(float x) {
  return __builtin_amdgcn_rcpf(1.f + __expf(-x));
}
__device__ __forceinline__ float tanhff(float x) {
  return 1.f - 2.f * __builtin_amdgcn_rcpf(__expf(2.f * x) + 1.f);
}

__device__ __forceinline__ half8 cvt8(const float* __restrict__ p) {
  f32x4 v0 = *(const f32x4*)p;
  f32x4 v1 = *(const f32x4*)(p + 4);
  half8 r;
  r[0] = (_Float16)v0[0]; r[1] = (_Float16)v0[1]; r[2] = (_Float16)v0[2]; r[3] = (_Float16)v0[3];
  r[4] = (_Float16)v1[0]; r[5] = (_Float16)v1[1]; r[6] = (_Float16)v1[2]; r[7] = (_Float16)v1[3];
  return r;
}
#define MFMA(a, b, c) __builtin_amdgcn_mfma_f32_16x16x32_f16(a, b, c, 0, 0, 0)

// ------- done normalize -> u64 bitmask  +  w_hh -> fragment-ordered f16 -----
// whhF[(((wc*4+kt)*4+ty)*64 + lg*16+lr)*8 + e] = whh[g][k],
//   g = ty*128 + wc*16 + lr, k = kt*32 + lg*8 + e  (matches k_lstm frag reads)
__global__ __launch_bounds__(256) void k_done(const unsigned char* __restrict__ raw,
                                              const float* __restrict__ whh,
                                              unsigned long long* __restrict__ dmask,
                                              _Float16* __restrict__ whhF) {
  __shared__ int f0, f1;
  if (threadIdx.x == 0) { f0 = 0; f1 = 0; }
  __syncthreads();
  int l0 = 0, l1 = 0;
  for (int i = threadIdx.x; i < 16384; i += 256)
    if (raw[i]) { if (i & 3) l0 = 1; else l1 = 1; }
  if (l0) atomicOr(&f0, 1);
  if (l1) atomicOr(&f1, 1);
  __syncthreads();
  int mode = (f0 && f1) ? 0 : (f1 ? 1 : (f0 ? 2 : 0));
  const int t = blockIdx.x;
  if (threadIdx.x < 64) {
    int i = t * 64 + threadIdx.x;
    bool v;
    if (mode == 0)      v = raw[i] != 0;
    else if (mode == 1) v = ((const int*)raw)[i] != 0;
    else                v = (((const float*)raw)[i] != 0.f);
    unsigned long long m = __ballot(v);
    if (threadIdx.x == 0) dmask[t] = m;
  }
  // w_hh permute: 65536 elems over 65536 threads
  {
    int i = blockIdx.x * 256 + threadIdx.x;
    int g = i >> 7, k = i & 127;
    int wc = (g >> 4) & 7, lr = g & 15, ty = g >> 7;
    int kt = k >> 5, lg = (k >> 3) & 3, e = k & 7;
    whhF[(((wc * 4 + kt) * 4 + ty) * 64 + lg * 16 + lr) * 8 + e] = (_Float16)whh[i];
  }
}

// ---------------- conv stack + readin + xgates (all-MFMA) -------------------
// block = (t, b-half) = 32 samples, 512 threads / 8 waves; 78.4 KB LDS.
// launch_bounds(512,2): LDS already caps residency at 2 blocks/CU
// (2 x 80256 B <= 160 KiB), so the old (512,4) VGPR-64 cap bought nothing
// and risked silent spill; (512,2) gives the same 2-block residency with a
// 128-reg budget.
__global__ __launch_bounds__(512, 2) void k_conv(
    const float* __restrict__ inp,
    const float* __restrict__ c1w, const float* __restrict__ c1b,
    const float* __restrict__ c2w, const float* __restrict__ c2b,
    const float* __restrict__ c3w, const float* __restrict__ c3b,
    const float* __restrict__ riw, const float* __restrict__ rib,
    const float* __restrict__ wih, const float* __restrict__ bih,
    const float* __restrict__ bhh,
    _Float16* __restrict__ xgh)   // [256 t][512 gate][64 b] f16
{
  extern __shared__ char L[];
  unsigned*  LUT32 = (unsigned*)L;              // [32] u32, 128 B
  _Float16*  ic1   = (_Float16*)(L + 128);      // [256][32] f16 swz, 16384 B
  _Float16*  a1t   = (_Float16*)(L + 16512);    // [16][1160] f16, 37120 B
  _Float16*  a2    = (_Float16*)(L + 53632);    // [32][128] f16 swz, 8192 B
  _Float16*  c2wL  = (_Float16*)(L + 61824);    // [32 o][9 tap][32 i] f16, 18432 B
  _Float16*  ft    = (_Float16*)(L + 128);      // overlay (ic1/a1t dead)
  _Float16*  yb    = (_Float16*)(L + 8320);     // overlay

  const int tid  = threadIdx.x;
  const int lane = tid & 63;
  const int wv   = tid >> 6;        // 0..7
  const int lr   = lane & 15;
  const int lg   = lane >> 4;
  const int t    = blockIdx.x >> 1;
  const int bh   = blockIdx.x & 1;

  const int ntl  = wv & 1;          // n-tile for conv1/conv2 (o = ntl*16+lr)
  const int mq   = wv >> 1;         // m-group
  const int o1   = ntl * 16 + lr;

  if (tid < 32) {
    unsigned v = 0xFFFFFFFFu;
    if (tid < 27) { int c = tid / 9, r9 = tid % 9; v = (unsigned)(c | ((r9 / 3) << 8) | ((r9 % 3) << 16)); }
    LUT32[tid] = v;
  }

  // stage c2w -> LDS transposed [o][tap][i] (f16)
  if (tid < 128) {
    const int o = tid >> 2, lg2 = tid & 3;
    const float* src = c2w + o * 288 + lg2 * 72;
    #pragma unroll 4
    for (int j = 0; j < 72; ++j) {
      int i = lg2 * 8 + j / 9, tap = j % 9;
      c2wL[(o * 9 + tap) * 32 + i] = (_Float16)src[j];
    }
  }

  half8 B1;
  #pragma unroll
  for (int e = 0; e < 8; ++e) {
    int k = lg * 8 + e;
    B1[e] = (_Float16)((k < 27) ? c1w[o1 * 27 + k] : 0.f);
  }
  const float b1o = c1b[o1];
  const float b2o = c2b[o1];

  for (int ch = 0; ch < 2; ++ch) {        // 2 chunks x 16 samples
    __syncthreads();                      // also orders c2wL staging (ch=0)
    for (int i = tid; i < 18560 / 2; i += 512) ((unsigned*)a1t)[i] = 0u;
    {
      const size_t n0 = (size_t)(t * 64 + bh * 32 + ch * 16) * 147;
      #pragma unroll 4
      for (int j = 0; j < 16; ++j) {
        int e = tid + j * 512;            // 0..8191
        int row = e >> 5, k = e & 31;
        int s = row >> 4, pos = row & 15;
        int p = pos >> 2, q = pos & 3;
        unsigned lut = LUT32[k];
        float v = 0.f;
        if (lut != 0xFFFFFFFFu) {
          int c = lut & 0xFF, dp = (lut >> 8) & 0xFF, dq = (lut >> 16) & 0xFF;
          int pp = 2 * p + dp - 1, qq = 2 * q + dq - 1;
          if ((unsigned)pp < 7u && (unsigned)qq < 7u)
            v = inp[n0 + s * 147 + qq * 21 + pp * 3 + c];
        }
        ic1[row * 32 + (k ^ ((row & 3) << 3))] = (_Float16)v;
      }
    }
    __syncthreads();
    #pragma unroll
    for (int mi = 0; mi < 4; ++mi) {
      const int mtile = mq * 4 + mi;
      const int rowA  = mtile * 16 + lr;
      half8 a = *(const half8*)(ic1 + rowA * 32 + ((lg * 8) ^ ((rowA & 3) << 3)));
      f32x4 acc; acc[0] = b1o; acc[1] = b1o; acc[2] = b1o; acc[3] = b1o;
      acc = MFMA(a, B1, acc);
      #pragma unroll
      for (int r = 0; r < 4; ++r) {
        int m1 = mtile * 16 + lg * 4 + r;
        int s = m1 >> 4, pos = m1 & 15;
        int p = pos >> 2, q = pos & 3;
        int xy = (p + 1) * 6 + (q + 1);
        a1t[s * 1160 + xy * 32 + (o1 ^ ((xy & 3) << 3))] = (_Float16)eluf(acc[r]);
      }
    }
    __syncthreads();
    {
      f32x4 acc; acc[0] = b2o; acc[1] = b2o; acc[2] = b2o; acc[3] = b2o;
      const int rowm = mq * 16 + lr;
      const int s2 = rowm >> 2, pos2 = rowm & 3;
      const int p2 = pos2 >> 1, q2 = pos2 & 1;
      #pragma unroll
      for (int tap = 0; tap < 9; ++tap) {
        const int dp = tap / 3, dq = tap % 3;
        const int xy2 = (2 * p2 + dp) * 6 + (2 * q2 + dq);
        half8 a  = *(const half8*)(a1t + s2 * 1160 + xy2 * 32 + ((lg * 8) ^ ((xy2 & 3) << 3)));
        half8 b2 = *(const half8*)(c2wL + (o1 * 9 + tap) * 32 + lg * 8);
        acc = MFMA(a, b2, acc);
      }
      #pragma unroll
      for (int r = 0; r < 4; ++r) {
        int m = mq * 16 + lg * 4 + r;
        int s2w = m >> 2, pos = m & 3;
        int arow = ch * 16 + s2w;
        int col = o1 * 4 + pos;
        a2[arow * 128 + (col ^ ((arow & 7) << 3))] = (_Float16)eluf(acc[r]);
      }
    }
  }
  __syncthreads();

  // conv3 GEMM: M=32, K=128, N=128
  {
    half8 B3[4];
    #pragma unroll
    for (int kt = 0; kt < 4; ++kt) {
      half8 b;
      #pragma unroll
      for (int e = 0; e < 8; ++e) {
        int k = kt * 32 + lg * 8 + e;
        int i = k >> 2, pos = k & 3;
        int widx = 4 + (pos >> 1) * 3 + (pos & 1);
        b[e] = (_Float16)c3w[(wv * 16 + lr) * 288 + i * 9 + widx];
      }
      B3[kt] = b;
    }
    float bb = c3b[wv * 16 + lr];
    #pragma unroll
    for (int mt = 0; mt < 2; ++mt) {
      f32x4 acc; acc[0] = bb; acc[1] = bb; acc[2] = bb; acc[3] = bb;
      const int row = mt * 16 + lr;
      #pragma unroll
      for (int kt = 0; kt < 4; ++kt) {
        half8 a = *(const half8*)(a2 + row * 128 + ((kt * 32 + lg * 8) ^ ((row & 7) << 3)));
        acc = MFMA(a, B3[kt], acc);
      }
      #pragma unroll
      for (int r = 0; r < 4; ++r) {
        int m = mt * 16 + lg * 4 + r;
        ft[m * 128 + ((wv * 16 + lr) ^ ((m & 7) << 3))] = (_Float16)eluf(acc[r]);
      }
    }
  }
  __syncthreads();

  // GEMM1: y = ft @ riw^T + rib
  {
    half8 R1[4];
    #pragma unroll
    for (int kt = 0; kt < 4; ++kt)
      R1[kt] = cvt8(riw + (wv * 16 + lr) * 128 + kt * 32 + lg * 8);
    float bb = rib[wv * 16 + lr];
    #pragma unroll
    for (int mt = 0; mt < 2; ++mt) {
      f32x4 acc; acc[0] = bb; acc[1] = bb; acc[2] = bb; acc[3] = bb;
      const int row = mt * 16 + lr;
      #pragma unroll
      for (int kt = 0; kt < 4; ++kt) {
        half8 a = *(const half8*)(ft + row * 128 + ((kt * 32 + lg * 8) ^ ((row & 7) << 3)));
        acc = MFMA(a, R1[kt], acc);
      }
      #pragma unroll
      for (int r = 0; r < 4; ++r) {
        int m = mt * 16 + lg * 4 + r;
        yb[m * 128 + ((wv * 16 + lr) ^ ((m & 7) << 3))] = (_Float16)acc[r];
      }
    }
  }
  __syncthreads();

  // GEMM2: xg = y @ wih^T + (bih + bhh)
  {
    #pragma unroll
    for (int mt = 0; mt < 2; ++mt) {
      const int row = mt * 16 + lr;
      half8 a[4];
      #pragma unroll
      for (int kt = 0; kt < 4; ++kt)
        a[kt] = *(const half8*)(yb + row * 128 + ((kt * 32 + lg * 8) ^ ((row & 7) << 3)));
      #pragma unroll
      for (int ty = 0; ty < 4; ++ty) {
        int g = ty * 128 + wv * 16 + lr;
        float bg = bih[g] + bhh[g];
        f32x4 acc; acc[0] = bg; acc[1] = bg; acc[2] = bg; acc[3] = bg;
        #pragma unroll
        for (int kt = 0; kt < 4; ++kt) {
          half8 w = cvt8(wih + g * 128 + kt * 32 + lg * 8);
          acc = MFMA(a[kt], w, acc);
        }
        half4 h4;
        h4[0] = (_Float16)acc[0]; h4[1] = (_Float16)acc[1];
        h4[2] = (_Float16)acc[2]; h4[3] = (_Float16)acc[3];
        *(half4*)(xgh + ((size_t)t * 512 + g) * 64 + bh * 32 + mt * 16 + lg * 4) = h4;
      }
    }
  }
}

// ---------------- windowed LSTM (16 steps, MFMA) + readout ------------------
// block = (t, b-quarter) = 16 samples, 512 thr / 8 waves, grid 1024.
// R18 configuration — measured optimum of the {full, 2, 1} unroll sweep.
__global__ __launch_bounds__(512, 4) void k_lstm(
    const _Float16* __restrict__ whhF, const float* __restrict__ bih,
    const float* __restrict__ bhh, const _Float16* __restrict__ xgh,
    const unsigned long long* __restrict__ dmask,
    const float* __restrict__ row_, const float* __restrict__ rob,
    float* __restrict__ out)
{
  __shared__ _Float16 H[2][16 * 128];   // 8 KB, XOR-swizzled rows

  const int tid  = threadIdx.x;
  const int lane = tid & 63;
  const int wv   = tid >> 6;            // cell group: cells wv*16 + lr
  const int lr   = lane & 15, lg = lane >> 4;
  const int xcd  = blockIdx.x & 7;
  const int j    = blockIdx.x >> 3;     // 0..127 per XCD
  const int t    = (xcd << 5) + (j >> 2);
  const int bq   = j & 3;               // b-quarter
  const int bbase = bq * 16;

  const _Float16* wbase = whhF + (size_t)wv * 8192 + lane * 8;  // frag base

  float b0[4];
  #pragma unroll
  for (int ty = 0; ty < 4; ++ty) {
    int g = ty * 128 + wv * 16 + lr;
    b0[ty] = bih[g] + bhh[g];
  }

  for (int i = tid; i < 16 * 128 / 2; i += 512) ((unsigned*)H[0])[i] = 0u;

  float cc[4];   // [r]: local sample lg*4 + r, cell wv*16+lr
  #pragma unroll
  for (int r = 0; r < 4; ++r) cc[r] = 0.f;

  for (int st = 0; st < 16; ++st) {
    const int ts = t + st - 15;
    _Float16* Hr = H[st & 1];
    _Float16* Hw = H[(st & 1) ^ 1];
    __syncthreads();
    const bool hasX = (ts >= 0);
    const unsigned long long wm =
        (st < 15 && ts + 1 >= 0) ? dmask[ts + 1] : 0ULL;
    const _Float16* xb = xgh + (size_t)ts * 32768 + bbase;
    f32x4 acc[4];   // [ty]
    if (hasX) {
      #pragma unroll
      for (int ty = 0; ty < 4; ++ty) {
        half4 p = *(const half4*)(xb + (ty * 128 + wv * 16 + lr) * 64 + lg * 4);
        acc[ty][0] = (float)p[0]; acc[ty][1] = (float)p[1];
        acc[ty][2] = (float)p[2]; acc[ty][3] = (float)p[3];
      }
    } else {
      #pragma unroll
      for (int ty = 0; ty < 4; ++ty) {
        acc[ty][0] = b0[ty]; acc[ty][1] = b0[ty];
        acc[ty][2] = b0[ty]; acc[ty][3] = b0[ty];
      }
    }
    #pragma unroll
    for (int kt = 0; kt < 4; ++kt) {
      half8 a0 = *(const half8*)(Hr + lr * 128 + ((kt * 32 + lg * 8) ^ ((lr & 7) << 3)));
      // per-ty load->MFMA pairs (R18 best)
      #pragma unroll
      for (int ty = 0; ty < 4; ++ty) {
        half8 wf = *(const half8*)(wbase + (kt * 4 + ty) * 512);
        acc[ty] = MFMA(a0, wf, acc[ty]);
      }
    }
    const unsigned mnib = (unsigned)(wm >> (bbase + lg * 4)) & 15u;
    #pragma unroll
    for (int r = 0; r < 4; ++r) {
      const int s_ = lg * 4 + r;                  // local sample 0..15
      const bool d = (mnib >> r) & 1u;
      float iv = sigf(acc[0][r]);
      float fv = sigf(acc[1][r]);
      float gv = tanhff(acc[2][r]);
      float ov = sigf(acc[3][r]);
      float cn = fmaf(fv, cc[r], iv * gv);
      float hn = ov * tanhff(cn);
      cc[r] = d ? 0.f : cn;
      Hw[s_ * 128 + ((wv * 16 + lr) ^ ((s_ & 7) << 3))] = (_Float16)(d ? 0.f : hn);
    }
  }
  __syncthreads();

  // readout: out = h_final @ row_^T + rob  (h_final in H[0] after st=15)
  float rb2 = rob[wv * 16 + lr];
  {
    const int row = lr;
    f32x4 acc; acc[0] = rb2; acc[1] = rb2; acc[2] = rb2; acc[3] = rb2;
    #pragma unroll
    for (int kt = 0; kt < 4; ++kt) {
      half8 R = cvt8(row_ + (wv * 16 + lr) * 128 + kt * 32 + lg * 8);
      half8 a = *(const half8*)(H[0] + row * 128 + ((kt * 32 + lg * 8) ^ ((row & 7) << 3)));
      acc = MFMA(a, R, acc);
    }
    #pragma unroll
    for (int r = 0; r < 4; ++r) {
      int s = lg * 4 + r;
      out[(size_t)(t * 64 + bbase + s) * 128 + wv * 16 + lr] = acc[r];
    }
  }
}

extern "C" void kernel_launch(void* const* d_in, const int* in_sizes, int n_in,
                              void* d_out, int out_size, void* d_ws, size_t ws_size,
                              hipStream_t stream) {
  const float* inp = (const float*)d_in[0];
  const void*  don = d_in[1];
  const float* c1w = (const float*)d_in[2];
  const float* c1b = (const float*)d_in[3];
  const float* c2w = (const float*)d_in[4];
  const float* c2b = (const float*)d_in[5];
  const float* c3w = (const float*)d_in[6];
  const float* c3b = (const float*)d_in[7];
  const float* riw = (const float*)d_in[8];
  const float* rib = (const float*)d_in[9];
  const float* wih = (const float*)d_in[10];
  const float* whh = (const float*)d_in[11];
  const float* bih = (const float*)d_in[12];
  const float* bhh = (const float*)d_in[13];
  const float* row_ = (const float*)d_in[14];
  const float* rob = (const float*)d_in[15];

  unsigned long long* dmask = (unsigned long long*)d_ws;        // 2 KB @ 0
  _Float16* whhF = (_Float16*)((char*)d_ws + 16384);            // 128 KB
  _Float16* xgh  = (_Float16*)((char*)d_ws + 16384 + 131072);   // 16.8 MB f16

  (void)hipFuncSetAttribute((const void*)k_conv,
                            hipFuncAttributeMaxDynamicSharedMemorySize, 80256);

  k_done<<<256, 256, 0, stream>>>((const unsigned char*)don, whh, dmask, whhF);
  k_conv<<<512, 512, 80256, stream>>>(inp, c1w, c1b, c2w, c2b, c3w, c3b,
                                      riw, rib, wih, bih, bhh, xgh);
  k_lstm<<<1024, 512, 0, stream>>>(whhF, bih, bhh, xgh, dmask, row_, rob,
                                   (float*)d_out);
}